// Round 2
// 422.793 us; speedup vs baseline: 1.0363x; 1.0363x over previous
//
#include <hip/hip_runtime.h>
#include <cstddef>

#define PI_F 3.14159265358979323846f
#define TOTAL_TEX 349440
#define NC 32
#define LP 257   // LDS pad stride for K1 (257 % 32 == 1 -> conflict-free writes)

typedef float nf4 __attribute__((ext_vector_type(4)));

__constant__ int c_offs[6] = {0, 262144, 327680, 344064, 348160, 349184};

// ---- bf16 helpers (RNE) ---------------------------------------------------
static __device__ inline unsigned int f2bf(float x) {
  union { float f; unsigned int u; } v; v.f = x;
  return (v.u + 0x7FFFu + ((v.u >> 16) & 1u)) >> 16;
}
static __device__ inline unsigned int pack2(float lo, float hi) {
  return f2bf(lo) | (f2bf(hi) << 16);
}
static __device__ inline float4 bf4(uint2 q) {
  union { unsigned int u; float f; } a;
  float4 r;
  a.u = q.x << 16;          r.x = a.f;
  a.u = q.x & 0xFFFF0000u;  r.y = a.f;
  a.u = q.y << 16;          r.z = a.f;
  a.u = q.y & 0xFFFF0000u;  r.w = a.f;
  return r;
}
static __device__ inline void bf8(uint4 q, float4& lo, float4& hi) {
  uint2 a, b;
  a.x = q.x; a.y = q.y;
  b.x = q.z; b.y = q.w;
  lo = bf4(a);
  hi = bf4(b);
}

// ---------------------------------------------------------------------------
// K1: transpose feature (C,6,512,512) -> bf16 pool level0 [6][512*512][C]
//     and produce fp32 pooled1 [6][256*256][C] (2x2 avg) in the same pass.
// Tile = 64x4 pixels, 256 threads.
// ---------------------------------------------------------------------------
__global__ __launch_bounds__(256) void k_transpose_pool(
    const float* __restrict__ feat, unsigned short* __restrict__ pool0,
    float* __restrict__ pooled1)
{
  __shared__ float tile[32 * LP];
  int blk = blockIdx.x;
  int tx = blk & 7;            // 8 x-tiles of 64
  int rem = blk >> 3;
  int ty = rem & 127;          // 128 y-tiles of 4
  int f = rem >> 7;
  int gx0 = tx << 6, gy0 = ty << 2;
  int tid = threadIdx.x;
  int lx = tid & 63, ly = tid >> 6;
  int pix = ly * 64 + lx;

  const float* fp = feat + ((size_t)f * 512 + (gy0 + ly)) * 512 + gx0 + lx;
#pragma unroll
  for (int c = 0; c < 32; ++c) {
    tile[c * LP + pix] = fp[(size_t)c * (6 * 512 * 512)];
  }
  __syncthreads();

  // level-0 bf16 transposed store
  size_t rowbase = ((size_t)f * TOTAL_TEX + (size_t)gy0 * 512 + gx0) * NC;
#pragma unroll
  for (int it = 0; it < 8; ++it) {
    int q = it * 256 + tid;          // 0..2047
    int texel = q >> 3, cg = q & 7;
    int tyy = texel >> 6, txx = texel & 63;
    float v0 = tile[(cg * 4 + 0) * LP + texel];
    float v1 = tile[(cg * 4 + 1) * LP + texel];
    float v2 = tile[(cg * 4 + 2) * LP + texel];
    float v3 = tile[(cg * 4 + 3) * LP + texel];
    uint2 pk; pk.x = pack2(v0, v1); pk.y = pack2(v2, v3);
    *(uint2*)(pool0 + rowbase + ((size_t)tyy * 512 + txx) * NC + cg * 4) = pk;
  }

  // fp32 pooled level-1 (32x2 pooled texels)
  size_t pbase = ((size_t)f * 65536 + (size_t)(gy0 >> 1) * 256 + (gx0 >> 1)) * NC;
#pragma unroll
  for (int it = 0; it < 8; ++it) {
    int e = it * 256 + tid;          // c fast(32), px(32), py(2)
    int c = e & 31, px = (e >> 5) & 31, py = e >> 10;
    int b0 = (2 * py) * 64 + 2 * px;
    float v = 0.25f * ((tile[c * LP + b0] + tile[c * LP + b0 + 1]) +
                       (tile[c * LP + b0 + 64] + tile[c * LP + b0 + 65]));
    pooled1[pbase + ((size_t)py * 256 + px) * NC + c] = v;
  }
}

// ---------------------------------------------------------------------------
// K3: 5x5 GGX specular filter + fused 2x2 avg-pool of the UNFILTERED input.
// Block = 32 pixels as a 16x2 tile (so the block holds whole pooling quads).
// Reads fp32 pooled[l], writes bf16 filtered level + fp32 pooled[l+1].
// ---------------------------------------------------------------------------
__device__ inline float3 face_dir_norm(int f, int i, int j, float inv2R)
{
  float u = ((float)j + 0.5f) * inv2R - 1.0f;
  float v = ((float)i + 0.5f) * inv2R - 1.0f;
  float x, y, z;
  switch (f) {
    case 0: x = 1.0f;  y = -v; z = -u;   break;
    case 1: x = -1.0f; y = -v; z = u;    break;
    case 2: x = u;  y = 1.0f;  z = v;    break;
    case 3: x = u;  y = -1.0f; z = -v;   break;
    case 4: x = u;  y = -v;    z = 1.0f; break;
    default: x = -u; y = -v;   z = -1.0f; break;
  }
  float s = 1.0f / sqrtf(x * x + y * y + z * z);
  float3 o; o.x = x * s; o.y = y * s; o.z = z * s;
  return o;
}

__global__ __launch_bounds__(256) void k_filter3(
    const float* __restrict__ in, unsigned short* __restrict__ out,
    float* __restrict__ pooled_out,       // nullptr for last level
    int R, int logR, float a2)
{
  __shared__ float wlds[32 * 26];
  __shared__ float4 clds[32][8];          // center taps for fused pooling
  int tid = threadIdx.x;
  float inv2R = 2.0f / (float)R;

  // tile decomposition: 16 wide x 2 tall
  int txi = blockIdx.x & ((R >> 4) - 1);
  int rest = blockIdx.x >> (logR - 4);
  int tyi = rest & ((R >> 1) - 1);
  int f = rest >> (logR - 1);
  int jbase = txi << 4, ibase = tyi << 1;

  {
    int pl = tid & 31;
    int tg = tid >> 5;
    int j = jbase + (pl & 15);
    int i = ibase + (pl >> 4);
    float3 dc = face_dir_norm(f, i, j, inv2R);
    for (int tap = tg; tap < 25; tap += 8) {
      int di = tap / 5 - 2;
      int dj = tap - (tap / 5) * 5 - 2;
      int ii = min(max(i + di, 0), R - 1);
      int jj = min(max(j + dj, 0), R - 1);
      float3 dn = face_dir_norm(f, ii, jj, inv2R);
      float cs = dc.x * dn.x + dc.y * dn.y + dc.z * dn.z;
      cs = fminf(fmaxf(cs, -1.0f), 1.0f);
      float den = cs * cs * (a2 - 1.0f) + 1.0f;
      float w = (cs > 0.0f) ? (a2 / (PI_F * den * den)) : 0.0f;
      wlds[pl * 26 + tap] = w;
    }
  }
  __syncthreads();

  int cg = tid & 7;
  int pl = tid >> 3;
  int j = jbase + (pl & 15);
  int i = ibase + (pl >> 4);
  const float4* fbase = (const float4*)(in + (((size_t)f << (2 * logR)) * NC));

  float4 acc; acc.x = acc.y = acc.z = acc.w = 0.0f;
  float4 cen; cen.x = cen.y = cen.z = cen.w = 0.0f;
  float wsum = 0.0f;
#pragma unroll
  for (int di = -2; di <= 2; ++di) {
    int ii = min(max(i + di, 0), R - 1);
    int rowb = ii * R;
#pragma unroll
    for (int dj = -2; dj <= 2; ++dj) {
      int jj = min(max(j + dj, 0), R - 1);
      int tap = (di + 2) * 5 + (dj + 2);
      float w = wlds[pl * 26 + tap];
      wsum += w;
      float4 v = fbase[(size_t)(rowb + jj) * 8 + cg];
      if (di == 0 && dj == 0) cen = v;     // compile-time branch (unrolled)
      acc.x += w * v.x; acc.y += w * v.y; acc.z += w * v.z; acc.w += w * v.w;
    }
  }
  float s = 1.0f / fmaxf(wsum, 1e-8f);
  uint2 pk;
  pk.x = pack2(acc.x * s, acc.y * s);
  pk.y = pack2(acc.z * s, acc.w * s);
  ((uint2*)(out + ((size_t)f * TOTAL_TEX + (size_t)(i * R + j)) * NC))[cg] = pk;

  // fused 2x2 avg-pool of unfiltered input -> pooled[l+1]
  if (pooled_out) {
    clds[pl][cg] = cen;
    __syncthreads();
    if (tid < 64) {
      int m = tid >> 3;      // local pooled x: 0..7
      int c = tid & 7;       // channel group
      float4 a = clds[0 * 16 + 2 * m][c];
      float4 b = clds[0 * 16 + 2 * m + 1][c];
      float4 cc = clds[16 + 2 * m][c];
      float4 d = clds[16 + 2 * m + 1][c];
      float4 r;
      r.x = 0.25f * ((a.x + b.x) + (cc.x + d.x));
      r.y = 0.25f * ((a.y + b.y) + (cc.y + d.y));
      r.z = 0.25f * ((a.z + b.z) + (cc.z + d.z));
      r.w = 0.25f * ((a.w + b.w) + (cc.w + d.w));
      int Rp = R >> 1;
      ((float4*)(pooled_out +
                 (((size_t)f * Rp + tyi) * Rp + (txi * 8 + m)) * NC))[c] = r;
    }
  }
}

// ---------------------------------------------------------------------------
// K4: fetch from bf16 pool. thread = (sample, channel-group of 8).
// 4 lanes cover one 64B texel via dwordx4 loads; half the threads/instrs of
// the previous 8-lane layout for identical bytes moved.
// ---------------------------------------------------------------------------
__global__ __launch_bounds__(256) void k_fetch4(
    const unsigned short* __restrict__ pool, const float* __restrict__ wv,
    const float* __restrict__ rv, float* __restrict__ out, int B)
{
  int t = blockIdx.x * 256 + threadIdx.x;
  int cg = t & 3;
  int b = t >> 2;
  if (b >= B) return;

  float dx = wv[3 * b + 0] * 2.0f - 1.0f;
  float dy = wv[3 * b + 1] * 2.0f - 1.0f;
  float dz = wv[3 * b + 2] * 2.0f - 1.0f;
  float ax = fabsf(dx), ay = fabsf(dy), az = fabsf(dz);
  bool condx = (ax >= ay) && (ax >= az);
  bool condy = (ay >= az) && !condx;
  float ma = condx ? ax : (condy ? ay : az);
  int face = condx ? (dx > 0.0f ? 0 : 1)
                   : (condy ? (dy > 0.0f ? 2 : 3) : (dz > 0.0f ? 4 : 5));
  float un = condx ? (dx > 0.0f ? -dz : dz)
                   : (condy ? dx : (dz > 0.0f ? dx : -dx));
  float vn = condx ? -dy : (condy ? (dy > 0.0f ? dz : -dz) : -dy);
  float u01 = (un / ma + 1.0f) * 0.5f;
  float v01 = (vn / ma + 1.0f) * 0.5f;

  float rr = rv[b];
  float lev_f = fminf(fmaxf((rr - 0.03f) / (0.99f - 0.03f), 0.0f), 1.0f) * 5.0f;
  int l0 = (int)floorf(lev_f);
  l0 = min(max(l0, 0), 5);
  int l1 = min(l0 + 1, 5);
  float tt = lev_f - (float)l0;

  float4 accA; accA.x = accA.y = accA.z = accA.w = 0.0f;
  float4 accB; accB.x = accB.y = accB.z = accB.w = 0.0f;
  int   lvs[2] = {l0, l1};
  float lws[2] = {1.0f - tt, tt};
#pragma unroll
  for (int s = 0; s < 2; ++s) {
    int l = lvs[s];
    float wl = lws[s];
    int res = 512 >> l;
    float rf = (float)res;
    float x = fminf(fmaxf(u01 * rf - 0.5f, 0.0f), rf - 1.0f);
    float y = fminf(fmaxf(v01 * rf - 0.5f, 0.0f), rf - 1.0f);
    int x0 = (int)floorf(x), y0 = (int)floorf(y);
    int x1 = min(x0 + 1, res - 1), y1 = min(y0 + 1, res - 1);
    float fx = x - (float)x0, fy = y - (float)y0;
    const uint4* base16 =
        (const uint4*)(pool + ((size_t)face * TOTAL_TEX + c_offs[l]) * NC);
    float w00 = wl * (1.0f - fx) * (1.0f - fy);
    float w01 = wl * fx * (1.0f - fy);
    float w10 = wl * (1.0f - fx) * fy;
    float w11 = wl * fx * fy;
    uint4 qa = base16[(size_t)(y0 * res + x0) * 4 + cg];
    uint4 qb = base16[(size_t)(y0 * res + x1) * 4 + cg];
    uint4 qc = base16[(size_t)(y1 * res + x0) * 4 + cg];
    uint4 qd = base16[(size_t)(y1 * res + x1) * 4 + cg];
    float4 lo, hi;
    bf8(qa, lo, hi);
    accA.x += w00 * lo.x; accA.y += w00 * lo.y; accA.z += w00 * lo.z; accA.w += w00 * lo.w;
    accB.x += w00 * hi.x; accB.y += w00 * hi.y; accB.z += w00 * hi.z; accB.w += w00 * hi.w;
    bf8(qb, lo, hi);
    accA.x += w01 * lo.x; accA.y += w01 * lo.y; accA.z += w01 * lo.z; accA.w += w01 * lo.w;
    accB.x += w01 * hi.x; accB.y += w01 * hi.y; accB.z += w01 * hi.z; accB.w += w01 * hi.w;
    bf8(qc, lo, hi);
    accA.x += w10 * lo.x; accA.y += w10 * lo.y; accA.z += w10 * lo.z; accA.w += w10 * lo.w;
    accB.x += w10 * hi.x; accB.y += w10 * hi.y; accB.z += w10 * hi.z; accB.w += w10 * hi.w;
    bf8(qd, lo, hi);
    accA.x += w11 * lo.x; accA.y += w11 * lo.y; accA.z += w11 * lo.z; accA.w += w11 * lo.w;
    accB.x += w11 * hi.x; accB.y += w11 * hi.y; accB.z += w11 * hi.z; accB.w += w11 * hi.w;
  }
  nf4* o = (nf4*)(out + (size_t)b * NC);
  nf4 va = {accA.x, accA.y, accA.z, accA.w};
  nf4 vb = {accB.x, accB.y, accB.z, accB.w};
  __builtin_nontemporal_store(va, o + cg * 2);
  __builtin_nontemporal_store(vb, o + cg * 2 + 1);
}

// ---------------------------------------------------------------------------
extern "C" void kernel_launch(void* const* d_in, const int* in_sizes, int n_in,
                              void* d_out, int out_size, void* d_ws, size_t ws_size,
                              hipStream_t stream)
{
  const float* feat = (const float*)d_in[0];
  const float* wv   = (const float*)d_in[1];
  const float* rv   = (const float*)d_in[2];
  float* out = (float*)d_out;
  int B = in_sizes[1] / 3;

  // ws layout: bf16 pool (134.2 MB) then fp32 pooled scratch (67.0 MB)
  unsigned short* pool_t = (unsigned short*)d_ws;
  const size_t POOLT = (size_t)6 * TOTAL_TEX * NC;      // bf16 elements
  float* pooled1 = (float*)(pool_t + POOLT);            // byte offset % 4 == 0
  float* pooled2 = pooled1 + (size_t)6 * 256 * 256 * NC;
  float* pooled3 = pooled2 + (size_t)6 * 128 * 128 * NC;
  float* pooled4 = pooled3 + (size_t)6 * 64 * 64 * NC;
  float* pooled5 = pooled4 + (size_t)6 * 32 * 32 * NC;
  float* pooled[6] = {nullptr, pooled1, pooled2, pooled3, pooled4, pooled5};
  static const int offs[6] = {0, 262144, 327680, 344064, 348160, 349184};

  hipLaunchKernelGGL(k_transpose_pool, dim3(6 * 8 * 128), dim3(256), 0, stream,
                     feat, pool_t, pooled1);

  for (int l = 1; l <= 5; ++l) {
    int R = 512 >> l;
    int logR = 9 - l;
    double rough_d = 0.03 + 0.192 * (double)l;   // linspace(0.03,0.99,6)
    float r32 = (float)rough_d;
    double alpha = (double)r32 * (double)r32;
    float a2 = (float)(alpha * alpha);
    int npix = 6 * R * R;
    float* pout = (l < 5) ? pooled[l + 1] : nullptr;
    hipLaunchKernelGGL(k_filter3, dim3(npix / 32), dim3(256), 0, stream,
                       pooled[l], pool_t + (size_t)offs[l] * NC, pout, R, logR, a2);
  }

  hipLaunchKernelGGL(k_fetch4, dim3((B * 4 + 255) / 256), dim3(256), 0, stream,
                     pool_t, wv, rv, out, B);
}